// Round 5
// baseline (182.439 us; speedup 1.0000x reference)
//
#include <hip/hip_runtime.h>
#include <hip/hip_bf16.h>

// EdgeWeightFromDistance: out[e] = relu(relu([x[src], y[dst], dist] @ W1 + b1) @ W2 + b2)
// E = 1e6, NODE_DIM = 64, HIDDEN = 128.
// R9 == R7 semantics, restructured: COMPUTE is a plain __forceinline__ function
//     (R5-style, known to compile+run) instead of a [&] lambda — the lambda was the
//     only structurally-new element in the twice-failed R7/R8 source.
// Content (unchanged from R7):
//     (a) LDS chunk swizzle p=((c-2*(r&7))&15) + bg4 fold-read broadcast across quads
//         (fixes the real conflict: quad0 vs quads1-3 same-slot/diff-addr 4-way on bg4).
//     (b) 3-stage pipeline (idx 2 tiles ahead, pos+frags 1 ahead) on R6's
//         acc[4]x2-half 8-indep-chain MFMA core. (256,3), grid 768.
//     Accumulation order unchanged -> bit-identical output.

constexpr int NDIM  = 64;
constexpr int HID   = 128;
constexpr int KPAD  = 136;          // shorts per Wt row: 17 chunks of 8 shorts (16 B)

typedef __attribute__((ext_vector_type(8))) short  short8;
typedef __attribute__((ext_vector_type(4))) int    int4v;
typedef __attribute__((ext_vector_type(4))) float  floatx4;

__device__ __forceinline__ short f2bf(float f) {
    union { __hip_bfloat16 h; short s; } cv;
    cv.h = __float2bfloat16(f);
    return cv.s;
}

__device__ __forceinline__ int pack2(float a, float b) {
    union { __hip_bfloat162 h; int u; } cv;
    cv.h = __float22bfloat162_rn(float2{a, b});
    return cv.u;
}

__device__ __forceinline__ short8 make_afrag_f32(const float* rp) {
    const floatx4 f0 = *reinterpret_cast<const floatx4*>(rp);
    const floatx4 f1 = *reinterpret_cast<const floatx4*>(rp + 4);
    union { int4v i; short8 s8; } cv;
    cv.i.x = pack2(f0.x, f0.y);
    cv.i.y = pack2(f0.z, f0.w);
    cv.i.z = pack2(f1.x, f1.y);
    cv.i.w = pack2(f1.z, f1.w);
    return cv.s8;
}

// ---- streaming fp32 -> bf16 convert of x and y into workspace ----
__global__ __launch_bounds__(256) void cvt_kernel(
    const float* __restrict__ xin, const float* __restrict__ yin,
    short* __restrict__ xb, short* __restrict__ yb, int nfl)
{
    const int stride = gridDim.x * blockDim.x;
    const int n8 = nfl >> 3;
    for (int i = blockIdx.x * blockDim.x + threadIdx.x; i < n8; i += stride) {
        {
            const floatx4 f0 = *reinterpret_cast<const floatx4*>(xin + i * 8);
            const floatx4 f1 = *reinterpret_cast<const floatx4*>(xin + i * 8 + 4);
            union { int4v v; short8 s; } c;
            c.v.x = pack2(f0.x, f0.y); c.v.y = pack2(f0.z, f0.w);
            c.v.z = pack2(f1.x, f1.y); c.v.w = pack2(f1.z, f1.w);
            *reinterpret_cast<short8*>(xb + i * 8) = c.s;
        }
        {
            const floatx4 f0 = *reinterpret_cast<const floatx4*>(yin + i * 8);
            const floatx4 f1 = *reinterpret_cast<const floatx4*>(yin + i * 8 + 4);
            union { int4v v; short8 s; } c;
            c.v.x = pack2(f0.x, f0.y); c.v.y = pack2(f0.z, f0.w);
            c.v.z = pack2(f1.x, f1.y); c.v.w = pack2(f1.z, f1.w);
            *reinterpret_cast<short8*>(yb + i * 8) = c.s;
        }
    }
}

// ---------------- pipeline stage buffers ----------------
struct IdxB  { int s0, d0, s1, d1; };
struct PosB  { float a0, a1, a2, b0, b1, b2; };   // lanes<32 only: px[ps], py[pd]
struct FragB { short8 fa[4]; short8 fb[4]; };
struct Offs  { int o0, o1, o2, o3, o4; };         // swizzled LDS short-offsets

__device__ __forceinline__ void load_idx(int tile, int wave, int lm, int E,
    const int* __restrict__ srcp, const int* __restrict__ dstp, IdxB& I)
{
    const int mb = tile * 128 + wave * 32;
    int m0 = mb + lm;       if (m0 >= E) m0 = E - 1;
    int m1 = mb + 16 + lm;  if (m1 >= E) m1 = E - 1;
    I.s0 = srcp[m0]; I.d0 = dstp[m0];
    I.s1 = srcp[m1]; I.d1 = dstp[m1];
}

__device__ __forceinline__ void load_pos(const IdxB& I, int lane,
    const float* __restrict__ px, const float* __restrict__ py, PosB& P)
{
    if (lane < 32) {
        const int ps = (lane < 16) ? I.s0 : I.s1;
        const int pd = (lane < 16) ? I.d0 : I.d1;
        P.a0 = px[ps * 3 + 0]; P.a1 = px[ps * 3 + 1]; P.a2 = px[ps * 3 + 2];
        P.b0 = py[pd * 3 + 0]; P.b1 = py[pd * 3 + 1]; P.b2 = py[pd * 3 + 2];
    }
}

template <bool BF16GATHER>
__device__ __forceinline__ void load_frags(const IdxB& I,
    const float* __restrict__ x, const float* __restrict__ y,
    const short* __restrict__ xb, const short* __restrict__ yb,
    int quad, FragB& F)
{
#pragma unroll
    for (int s = 0; s < 4; ++s) {
        const int kk = s * 32 + quad * 8;
        if (BF16GATHER) {
            const short* pa = (s < 2) ? (xb + I.s0 * NDIM + kk)
                                      : (yb + I.d0 * NDIM + (kk - 64));
            const short* pb = (s < 2) ? (xb + I.s1 * NDIM + kk)
                                      : (yb + I.d1 * NDIM + (kk - 64));
            F.fa[s] = *reinterpret_cast<const short8*>(pa);
            F.fb[s] = *reinterpret_cast<const short8*>(pb);
        } else {
            F.fa[s] = make_afrag_f32((s < 2) ? (x + I.s0 * NDIM + kk)
                                             : (y + I.d0 * NDIM + (kk - 64)));
            F.fb[s] = make_afrag_f32((s < 2) ? (x + I.s1 * NDIM + kk)
                                             : (y + I.d1 * NDIM + (kk - 64)));
        }
    }
}

// ---- compute core: R6's acc[4] x 2-half structure (bit-identical order) ----
__device__ __forceinline__ void compute_tile(
    const PosB& P, const FragB& F, int tl, int E,
    const short* __restrict__ Wt, const Offs& O,
    int lane, int lm, int quad, int wave,
    const float* w2v, float b2s, float* __restrict__ out)
{
    float dd = 0.f;
    if (lane < 32) {
        const float ax = P.a0 - P.b0;
        const float ay = P.a1 - P.b1;
        const float az = P.a2 - P.b2;
        dd = sqrtf(ax * ax + ay * ay + az * az);
    }
    const float dist0 = __shfl(dd, lm, 64);
    const float dist1 = __shfl(dd, lm + 16, 64);

    short8 fa4, fb4;
    {
        union { int4v i; short8 s8; } ca, cb;
        const int d0 = (quad == 0) ? pack2(dist0, 1.0f) : 0;
        const int d1 = (quad == 0) ? pack2(dist1, 1.0f) : 0;
        ca.i = int4v{d0, 0, 0, 0};
        cb.i = int4v{d1, 0, 0, 0};
        fa4 = ca.s8; fb4 = cb.s8;
    }

    float p0 = 0.f, p1 = 0.f, p2 = 0.f, p3 = 0.f;
    float q0 = 0.f, q1 = 0.f, q2 = 0.f, q3 = 0.f;

    // zoff guard defeats LICM of the (loop-invariant) Wt values (keeps regs low)
    int zoff = 0;
    asm volatile("" : "+v"(zoff));
    const short* wb = Wt + zoff;

#pragma unroll
    for (int half = 0; half < 2; ++half) {
        if (half) __builtin_amdgcn_sched_barrier(0);

        floatx4 aA[4], aB[4];
#pragma unroll
        for (int u = 0; u < 4; ++u) {
            aA[u] = floatx4{0.f, 0.f, 0.f, 0.f};
            aB[u] = floatx4{0.f, 0.f, 0.f, 0.f};
        }
#pragma unroll
        for (int u = 0; u < 4; ++u) {
            const int t = half * 4 + u;
            const short* wt = wb + t * (16 * KPAD);
            const short8 bg0 = *reinterpret_cast<const short8*>(wt + O.o0);
            const short8 bg1 = *reinterpret_cast<const short8*>(wt + O.o1);
            const short8 bg2 = *reinterpret_cast<const short8*>(wt + O.o2);
            const short8 bg3 = *reinterpret_cast<const short8*>(wt + O.o3);
            const short8 bg4 = *reinterpret_cast<const short8*>(wt + O.o4);
            aA[u] = __builtin_amdgcn_mfma_f32_16x16x32_bf16(F.fa[0], bg0, aA[u], 0, 0, 0);
            aB[u] = __builtin_amdgcn_mfma_f32_16x16x32_bf16(F.fb[0], bg0, aB[u], 0, 0, 0);
            aA[u] = __builtin_amdgcn_mfma_f32_16x16x32_bf16(F.fa[1], bg1, aA[u], 0, 0, 0);
            aB[u] = __builtin_amdgcn_mfma_f32_16x16x32_bf16(F.fb[1], bg1, aB[u], 0, 0, 0);
            aA[u] = __builtin_amdgcn_mfma_f32_16x16x32_bf16(F.fa[2], bg2, aA[u], 0, 0, 0);
            aB[u] = __builtin_amdgcn_mfma_f32_16x16x32_bf16(F.fb[2], bg2, aB[u], 0, 0, 0);
            aA[u] = __builtin_amdgcn_mfma_f32_16x16x32_bf16(F.fa[3], bg3, aA[u], 0, 0, 0);
            aB[u] = __builtin_amdgcn_mfma_f32_16x16x32_bf16(F.fb[3], bg3, aB[u], 0, 0, 0);
            aA[u] = __builtin_amdgcn_mfma_f32_16x16x32_bf16(fa4,     bg4, aA[u], 0, 0, 0);
            aB[u] = __builtin_amdgcn_mfma_f32_16x16x32_bf16(fb4,     bg4, aB[u], 0, 0, 0);
        }
#pragma unroll
        for (int u = 0; u < 4; ++u) {
            const float w = w2v[half * 4 + u];
            p0 += fmaxf(aA[u][0], 0.f) * w;
            p1 += fmaxf(aA[u][1], 0.f) * w;
            p2 += fmaxf(aA[u][2], 0.f) * w;
            p3 += fmaxf(aA[u][3], 0.f) * w;
            q0 += fmaxf(aB[u][0], 0.f) * w;
            q1 += fmaxf(aB[u][1], 0.f) * w;
            q2 += fmaxf(aB[u][2], 0.f) * w;
            q3 += fmaxf(aB[u][3], 0.f) * w;
        }
    }

#pragma unroll
    for (int off = 1; off < 16; off <<= 1) {
        p0 += __shfl_xor(p0, off, 64);
        p1 += __shfl_xor(p1, off, 64);
        p2 += __shfl_xor(p2, off, 64);
        p3 += __shfl_xor(p3, off, 64);
        q0 += __shfl_xor(q0, off, 64);
        q1 += __shfl_xor(q1, off, 64);
        q2 += __shfl_xor(q2, off, 64);
        q3 += __shfl_xor(q3, off, 64);
    }
    if (lm < 4) {
        const int mb = tl * 128 + wave * 32;
        const float vA = (lm == 0) ? p0 : (lm == 1) ? p1 : (lm == 2) ? p2 : p3;
        const float vB = (lm == 0) ? q0 : (lm == 1) ? q1 : (lm == 2) ? q2 : q3;
        const int eA = mb + quad * 4 + lm;
        const int eB = mb + 16 + quad * 4 + lm;
        if (eA < E) out[eA] = fmaxf(vA + b2s, 0.f);
        if (eB < E) out[eB] = fmaxf(vB + b2s, 0.f);
    }
}

template <bool BF16GATHER>
__global__ __launch_bounds__(256, 3) void edge_mlp_kernel(
    const float* __restrict__ x, const float* __restrict__ y,
    const short* __restrict__ xb, const short* __restrict__ yb,
    const int*  __restrict__ ei, const float* __restrict__ px,
    const float* __restrict__ py, const float* __restrict__ W1,
    const float* __restrict__ b1, const float* __restrict__ W2,
    const float* __restrict__ b2, float* __restrict__ out, int E)
{
    __shared__ __align__(16) short Wt[HID * KPAD];   // W1^T, chunk-swizzled per row

    const int tid = threadIdx.x;

    // ---- stage W1[0:128][0:128] transposed + chunk-swizzled into LDS ----
    // chunk c (16 B = 8 shorts) of row r stored at position ((c - 2*(r&7)) & 15)
    for (int base = 0; base < HID * HID; base += 256 * 8) {
        float f[8];
#pragma unroll
        for (int u = 0; u < 8; ++u) f[u] = W1[base + u * 256 + tid];
#pragma unroll
        for (int u = 0; u < 8; ++u) {
            const int i   = base + u * 256 + tid;
            const int row = i & 127;
            const int col = i >> 7;                       // 0..127 shorts
            const int p   = ((col >> 3) - 2 * (row & 7)) & 15;
            Wt[row * KPAD + p * 8 + (col & 7)] = f2bf(f[u]);
        }
    }
    // fold chunk 16 (never swizzled): k=128 -> w1r (dist coeff), k=129 -> b1, rest 0
    if (tid < HID) {
        const int n = tid;
        Wt[n * KPAD + 128] = f2bf(W1[128 * HID + n]);
        Wt[n * KPAD + 129] = f2bf(b1[n]);
#pragma unroll
        for (int j = 130; j < 136; ++j) Wt[n * KPAD + j] = 0;
    }
    __syncthreads();

    const int lane = tid & 63;
    const int wave = tid >> 6;
    const int quad = lane >> 4;
    const int lm   = lane & 15;   // A-frag row m; B-frag/C-D col n (within tile)

    float w2v[8];
#pragma unroll
    for (int t = 0; t < 8; ++t) w2v[t] = W2[t * 16 + lm];
    const float b2s = b2[0];

    const int* __restrict__ srcp = ei;
    const int* __restrict__ dstp = ei + E;

    // loop-invariant swizzled LDS short-offsets (chunk c = quad + 4s; row&7 == lm&7)
    Offs O;
    {
        const int r8 = lm & 7;
        O.o0 = lm * KPAD + (((quad +  0) - 2 * r8) & 15) * 8;
        O.o1 = lm * KPAD + (((quad +  4) - 2 * r8) & 15) * 8;
        O.o2 = lm * KPAD + (((quad +  8) - 2 * r8) & 15) * 8;
        O.o3 = lm * KPAD + (((quad + 12) - 2 * r8) & 15) * 8;
        O.o4 = lm * KPAD + 128;   // fold chunk 16, all quads (same-addr broadcast)
    }

    const int ntiles = (E + 127) / 128;       // 128 edges per block-iter, 32 per wave
    const int step = gridDim.x;
    int tile = blockIdx.x;
    if (tile >= ntiles) return;

    // ---- 3-stage pipeline: idx 2 ahead, pos+frags 1 ahead (all loads clamp-guarded) ----
    IdxB In; PosB Pc, Pn; FragB Fc, Fn;
    {
        IdxB I0;
        load_idx(tile, wave, lm, E, srcp, dstp, I0);
        load_pos(I0, lane, px, py, Pc);
        load_frags<BF16GATHER>(I0, x, y, xb, yb, quad, Fc);
    }
    load_idx(tile + step, wave, lm, E, srcp, dstp, In);

#pragma unroll 1
    for (;;) {
        // phase A: prefetch t+1 from In; idx t+2 -> In; compute tile t (Pc,Fc)
        load_frags<BF16GATHER>(In, x, y, xb, yb, quad, Fn);
        load_pos(In, lane, px, py, Pn);
        load_idx(tile + 2 * step, wave, lm, E, srcp, dstp, In);
        compute_tile(Pc, Fc, tile, E, Wt, O, lane, lm, quad, wave, w2v, b2s, out);
        tile += step;
        if (tile >= ntiles) break;

        // phase B: roles swapped
        load_frags<BF16GATHER>(In, x, y, xb, yb, quad, Fc);
        load_pos(In, lane, px, py, Pc);
        load_idx(tile + 2 * step, wave, lm, E, srcp, dstp, In);
        compute_tile(Pn, Fn, tile, E, Wt, O, lane, lm, quad, wave, w2v, b2s, out);
        tile += step;
        if (tile >= ntiles) break;
    }
}

extern "C" void kernel_launch(void* const* d_in, const int* in_sizes, int n_in,
                              void* d_out, int out_size, void* d_ws, size_t ws_size,
                              hipStream_t stream)
{
    const float* x  = (const float*)d_in[0];
    const float* y  = (const float*)d_in[1];
    const int*   ei = (const int*)  d_in[2];
    const float* px = (const float*)d_in[3];
    const float* py = (const float*)d_in[4];
    const float* W1 = (const float*)d_in[5];
    const float* b1 = (const float*)d_in[6];
    const float* W2 = (const float*)d_in[7];
    const float* b2 = (const float*)d_in[8];
    float* out = (float*)d_out;
    const int E = in_sizes[2] / 2;
    const int nnode_elems = in_sizes[0];             // N_NODES * 64

    const size_t need = (size_t)nnode_elems * 2 * sizeof(short);
    if (ws_size >= need) {
        short* xb = (short*)d_ws;
        short* yb = xb + nnode_elems;
        cvt_kernel<<<dim3(1024), dim3(256), 0, stream>>>(x, y, xb, yb, nnode_elems);
        edge_mlp_kernel<true><<<dim3(768), dim3(256), 0, stream>>>(
            x, y, xb, yb, ei, px, py, W1, b1, W2, b2, out, E);
    } else {
        edge_mlp_kernel<false><<<dim3(768), dim3(256), 0, stream>>>(
            x, y, nullptr, nullptr, ei, px, py, W1, b1, W2, b2, out, E);
    }
}